// Round 1
// baseline (2464.126 us; speedup 1.0000x reference)
//
#include <hip/hip_runtime.h>
#include <math.h>

#define NA 10000
#define FD 128
#define KR 64
#define DEGC 32
#define NE (NA*DEGC)
#define NOUTS_C 2005
#define NOUT_FINAL 2001

__device__ __forceinline__ float sspf(float x){
    // softplus(x) - log(2), numerically stable
    return fmaxf(x, 0.0f) + log1pf(expf(-fabsf(x))) - 0.6931471805599453f;
}

// ---------------- edge geometry ----------------
__global__ void k_dij(const float* __restrict__ R, const int* __restrict__ idx_i,
                      const int* __restrict__ idx_j, float* __restrict__ dij_out){
    int e = blockIdx.x*256 + threadIdx.x;
    if (e >= NE) return;
    int i = idx_i[e], j = idx_j[e];
    float dx = R[i*3+0] - R[j*3+0];
    float dy = R[i*3+1] - R[j*3+1];
    float dz = R[i*3+2] - R[j*3+2];
    float d2 = dx*dx + dy*dy + dz*dz;
    dij_out[e] = sqrtf(fmaxf(d2, 0.0f));
}

__global__ void k_rbf(const float* __restrict__ dij_in, float* __restrict__ rbf,
                      float gamma, float mu0, float dmu){
    int gid = blockIdx.x*256 + threadIdx.x;   // NE*KR = 20.48M < 2^31
    int e = gid >> 6, k = gid & 63;
    float d = dij_in[e];
    float t = d * 0.1f;
    float cut = 0.0f;
    if (d < 10.0f){
        float t2 = t*t, t3 = t2*t, t4 = t2*t2, t5 = t4*t;
        cut = 1.0f - 6.0f*t5 + 15.0f*t4 - 10.0f*t3;
    }
    float mu = mu0 + (float)k * dmu;
    float u = expf(-d) - mu;
    rbf[gid] = cut * expf(-gamma*u*u);
}

// ---------------- init: copy Qa, mol sums of input charges ----------------
__global__ void k_init(const float* __restrict__ QaAin, const float* __restrict__ QaBin,
                       const int* __restrict__ mol, float* __restrict__ QaA,
                       float* __restrict__ QaB, float* __restrict__ QAmol,
                       float* __restrict__ QBmol){
    int a = blockIdx.x*256 + threadIdx.x;
    if (a >= NA) return;
    float qa = QaAin[a], qb = QaBin[a];
    QaA[a] = qa; QaB[a] = qb;
    int m = mol[a];
    atomicAdd(&QAmol[m], qa);
    atomicAdd(&QBmol[m], qb);
}

// ---------------- embedding first layer (K=4) ----------------
__global__ void k_embed(const int* __restrict__ Z, const float* __restrict__ M,
                        const float* __restrict__ QaA, const float* __restrict__ QaB,
                        const float* __restrict__ W0, const float* __restrict__ b0,
                        float* __restrict__ h1){
    int gid = blockIdx.x*256 + threadIdx.x;
    if (gid >= NA*FD) return;
    int a = gid >> 7, c = gid & 127;
    float f0 = (float)Z[a], f1 = M[a], f2 = QaA[a], f3 = QaB[a];
    float v = b0[c] + f0*W0[c] + f1*W0[128+c] + f2*W0[256+c] + f3*W0[384+c];
    h1[gid] = sspf(v);
}

// ---------------- generic [N x 128] @ [128 x 128] ----------------
// MODE 0: Y = act(XW+b);  MODE 1: Y = add_src + act(XW+b);  MODE 2: Y = scale*add_src + (XW+b)
template<int IN_SSP, int OUT_SSP, int MODE>
__global__ __launch_bounds__(256) void k_mm128(
    const float* __restrict__ X, const float* __restrict__ W,
    const float* __restrict__ bias, float* __restrict__ Y,
    const float* __restrict__ add_src, const float* __restrict__ scale_vec)
{
    __shared__ float xs[16][132];          // pad 132 -> conflict-free
    const int tid = threadIdx.x;
    const int a0 = blockIdx.x * 16;        // 10000 = 625*16 exact
    for (int idx = tid; idx < 2048; idx += 256){
        int a = idx >> 7, k = idx & 127;
        float v = X[(size_t)(a0+a)*FD + k];
        if (IN_SSP) v = sspf(v);
        xs[a][k] = v;
    }
    __syncthreads();
    const int cq = tid & 31;               // col quad: cols cq*4..+3
    const int s  = tid >> 5;               // 0..7 -> atoms s, s+8
    float acc0[4] = {0.f,0.f,0.f,0.f};
    float acc1[4] = {0.f,0.f,0.f,0.f};
    const float4* W4 = (const float4*)W;
    for (int k4 = 0; k4 < 32; ++k4){
        float4 xa = *(const float4*)&xs[s][k4*4];
        float4 xb = *(const float4*)&xs[s+8][k4*4];
        #pragma unroll
        for (int kk = 0; kk < 4; ++kk){
            float4 w = W4[(k4*4+kk)*32 + cq];
            float va = (kk==0)?xa.x:((kk==1)?xa.y:((kk==2)?xa.z:xa.w));
            float vb = (kk==0)?xb.x:((kk==1)?xb.y:((kk==2)?xb.z:xb.w));
            acc0[0] += va*w.x; acc0[1] += va*w.y; acc0[2] += va*w.z; acc0[3] += va*w.w;
            acc1[0] += vb*w.x; acc1[1] += vb*w.y; acc1[2] += vb*w.z; acc1[3] += vb*w.w;
        }
    }
    float4 b4 = *(const float4*)(bias + cq*4);
    #pragma unroll
    for (int r = 0; r < 2; ++r){
        const float* accp = r ? acc1 : acc0;
        int a = a0 + s + 8*r;
        float v0 = accp[0] + b4.x;
        float v1 = accp[1] + b4.y;
        float v2 = accp[2] + b4.z;
        float v3 = accp[3] + b4.w;
        if (OUT_SSP){ v0 = sspf(v0); v1 = sspf(v1); v2 = sspf(v2); v3 = sspf(v3); }
        if (MODE == 1){
            float4 ad = *(const float4*)(add_src + (size_t)a*FD + cq*4);
            v0 += ad.x; v1 += ad.y; v2 += ad.z; v3 += ad.w;
        } else if (MODE == 2){
            float4 ad = *(const float4*)(add_src + (size_t)a*FD + cq*4);
            float4 sv = *(const float4*)(scale_vec + cq*4);
            v0 += sv.x*ad.x; v1 += sv.y*ad.y; v2 += sv.z*ad.z; v3 += sv.w*ad.w;
        }
        *(float4*)(Y + (size_t)a*FD + cq*4) = make_float4(v0,v1,v2,v3);
    }
}

// ---------------- message aggregation: m = xi + sum_e (rbf_e @ Wr) * xj[idx_j[e]] ----------------
__global__ __launch_bounds__(256) void k_agg(
    const float* __restrict__ rbf, const float* __restrict__ Wr,
    const int* __restrict__ idxj, const float* __restrict__ xi,
    const float* __restrict__ xj, float* __restrict__ mout)
{
    __shared__ float rb[2][DEGC][KR];      // 16 KB
    __shared__ int   jd[2][DEGC];
    __shared__ float part[2][4][FD];       // 4 KB
    const int tid = threadIdx.x;
    const int a0 = blockIdx.x * 2;         // 10000 = 5000*2 exact
    for (int idx = tid; idx < 2*DEGC*KR; idx += 256){
        int w = idx >> 11;
        int r = idx & 2047;
        rb[w][r >> 6][r & 63] = rbf[(size_t)(a0 + w)*DEGC*KR + r];
    }
    if (tid < 64) jd[tid >> 5][tid & 31] = idxj[(a0 + (tid >> 5))*DEGC + (tid & 31)];
    __syncthreads();
    const int aa = tid >> 7;               // atom within block (0..1)
    const int ta = tid & 127;
    const int cq = ta & 31;                // col quad
    const int s  = ta >> 5;                // edge group 0..3 (8 edges each)
    float g[8][4];
    #pragma unroll
    for (int t = 0; t < 8; ++t){ g[t][0]=0.f; g[t][1]=0.f; g[t][2]=0.f; g[t][3]=0.f; }
    const float4* W4 = (const float4*)Wr;
    for (int k = 0; k < KR; ++k){
        float4 w = W4[k*32 + cq];
        #pragma unroll
        for (int t = 0; t < 8; ++t){
            float r = rb[aa][s*8+t][k];
            g[t][0] += r*w.x; g[t][1] += r*w.y; g[t][2] += r*w.z; g[t][3] += r*w.w;
        }
    }
    float4 acc = make_float4(0.f,0.f,0.f,0.f);
    #pragma unroll
    for (int t = 0; t < 8; ++t){
        int j = jd[aa][s*8+t];
        float4 xv = *(const float4*)(xj + (size_t)j*FD + cq*4);
        acc.x += g[t][0]*xv.x; acc.y += g[t][1]*xv.y;
        acc.z += g[t][2]*xv.z; acc.w += g[t][3]*xv.w;
    }
    *(float4*)&part[aa][s][cq*4] = acc;
    __syncthreads();
    {
        int c = ta;
        int a = a0 + aa;
        float v = xi[(size_t)a*FD + c]
                + part[aa][0][c] + part[aa][1][c] + part[aa][2][c] + part[aa][3][c];
        mout[(size_t)a*FD + c] = v;
    }
}

// ---------------- j=0: out4 += ssp(xo) @ oW_i[:, 0:4] ----------------
__global__ void k_out4(const float* __restrict__ xo, const float* __restrict__ oWi,
                       float* __restrict__ out4){
    int gid = blockIdx.x*256 + threadIdx.x;
    int a = gid >> 6;
    int lane = threadIdx.x & 63;
    if (a >= NA) return;
    float y0 = sspf(xo[(size_t)a*FD + lane]);
    float y1 = sspf(xo[(size_t)a*FD + lane + 64]);
    const float* w0 = oWi + (size_t)lane*NOUTS_C;
    const float* w1 = oWi + (size_t)(lane+64)*NOUTS_C;
    float p0 = y0*w0[0] + y1*w1[0];
    float p1 = y0*w0[1] + y1*w1[1];
    float p2 = y0*w0[2] + y1*w1[2];
    float p3 = y0*w0[3] + y1*w1[3];
    #pragma unroll
    for (int off = 32; off > 0; off >>= 1){
        p0 += __shfl_down(p0, off);
        p1 += __shfl_down(p1, off);
        p2 += __shfl_down(p2, off);
        p3 += __shfl_down(p3, off);
    }
    if (lane == 0){
        out4[a*4+0] += p0; out4[a*4+1] += p1;
        out4[a*4+2] += p2; out4[a*4+3] += p3;
    }
}

// ---------------- charge equilibration ----------------
__global__ void k_molsum(const float* __restrict__ out4, const int* __restrict__ mol,
                         float* __restrict__ sums){
    int a = blockIdx.x*256 + threadIdx.x;
    if (a >= NA) return;
    int m = mol[a];
    atomicAdd(&sums[m],       out4[a*4+0]);
    atomicAdd(&sums[64+m],    out4[a*4+1]);
    atomicAdd(&sums[128+m],   out4[a*4+2]);
    atomicAdd(&sums[192+m],   out4[a*4+3]);
}

__global__ void k_qaupd(const float* __restrict__ out4, const int* __restrict__ mol,
                        const float* __restrict__ sums, const float* __restrict__ QAmol,
                        const float* __restrict__ QBmol, float* __restrict__ QaA,
                        float* __restrict__ QaB){
    int a = blockIdx.x*256 + threadIdx.x;
    if (a >= NA) return;
    int m = mol[a];
    float qa_n = out4[a*4+0], fa = out4[a*4+1];
    float qb_n = out4[a*4+2], fb = out4[a*4+3];
    QaA[a] = qa_n + fa * ((QAmol[m] - sums[m])      / sums[64+m]);
    QaB[a] = qb_n + fb * ((QBmol[m] - sums[128+m]) / sums[192+m]);
}

// ---------------- final fused head (j=1): outputs + nhloss, K=384 ----------------
__global__ __launch_bounds__(256) void k_final(
    const float* __restrict__ xo0, const float* __restrict__ xo1,
    const float* __restrict__ xo2, const float* __restrict__ oW,
    float* __restrict__ outp, float* __restrict__ nh_acc)
{
    __shared__ float yt[3*FD][16];     // transposed: [k][atom], broadcast b128 reads
    __shared__ float red[256];
    const int tid = threadIdx.x;
    const int a0 = blockIdx.x * 16;
    for (int idx = tid; idx < 16*3*FD; idx += 256){
        int a = idx & 15, kk = idx >> 4;
        const float* s = (kk < FD) ? xo0 : ((kk < 2*FD) ? xo1 : xo2);
        int k = kk & (FD-1);
        yt[kk][a] = sspf(s[(size_t)(a0 + a)*FD + k]);
    }
    __syncthreads();
    const int sg = tid >> 7;                       // atom group 0..1 (8 atoms)
    const int cc = tid & 127;
    const int col0 = blockIdx.y * 256 + cc;        // always < 2005 (max 1919)
    const bool v1 = (col0 + 128) < NOUTS_C;
    float oprev[8][2];
    float osum[8][2];
    float nh = 0.f;
    #pragma unroll
    for (int r = 0; r < 8; ++r){ osum[r][0] = 0.f; osum[r][1] = 0.f; }
    for (int seg = 0; seg < 3; ++seg){
        float acc[8][2];
        #pragma unroll
        for (int r = 0; r < 8; ++r){ acc[r][0] = 0.f; acc[r][1] = 0.f; }
        const float* Ws = oW + (size_t)seg*FD*NOUTS_C;
        for (int k = 0; k < FD; ++k){
            float w0 = Ws[(size_t)k*NOUTS_C + col0];
            float w1 = v1 ? Ws[(size_t)k*NOUTS_C + col0 + 128] : 0.f;
            const float* yrow = &yt[seg*FD + k][sg*8];
            float4 ya = *(const float4*)(yrow);
            float4 yb = *(const float4*)(yrow + 4);
            acc[0][0] += ya.x*w0; acc[0][1] += ya.x*w1;
            acc[1][0] += ya.y*w0; acc[1][1] += ya.y*w1;
            acc[2][0] += ya.z*w0; acc[2][1] += ya.z*w1;
            acc[3][0] += ya.w*w0; acc[3][1] += ya.w*w1;
            acc[4][0] += yb.x*w0; acc[4][1] += yb.x*w1;
            acc[5][0] += yb.y*w0; acc[5][1] += yb.y*w1;
            acc[6][0] += yb.z*w0; acc[6][1] += yb.z*w1;
            acc[7][0] += yb.w*w0; acc[7][1] += yb.w*w1;
        }
        #pragma unroll
        for (int r = 0; r < 8; ++r){
            #pragma unroll
            for (int q = 0; q < 2; ++q){
                float o = acc[r][q];
                osum[r][q] += o;
                if (seg > 0){
                    int A = a0 + sg*8 + r;
                    if (A >= 4){
                        float o2 = o*o;
                        float p = oprev[r][q];
                        nh += o2 / (o2 + p*p + 1e-7f);
                    }
                }
                oprev[r][q] = o;
            }
        }
    }
    #pragma unroll
    for (int r = 0; r < 8; ++r){
        int A = a0 + sg*8 + r;
        if (col0 >= 4){
            float v = osum[r][0];
            if (col0 > 4) v = fmaxf(v, 0.f);
            outp[(size_t)A*NOUT_FINAL + (col0 - 4)] = v;
        }
        if (v1){
            float v = fmaxf(osum[r][1], 0.f);   // col0+128 is always > 4
            outp[(size_t)A*NOUT_FINAL + (col0 + 128 - 4)] = v;
        }
    }
    red[tid] = nh;
    __syncthreads();
    for (int off = 128; off > 0; off >>= 1){
        if (tid < off) red[tid] += red[tid + off];
        __syncthreads();
    }
    if (tid == 0) atomicAdd(nh_acc, red[0]);
}

__global__ void k_finalize(const float* __restrict__ nh_acc, float* __restrict__ nh_out){
    *nh_out = *nh_acc * (1.0f / (float)((NA - 4) * NOUTS_C));
}

// =====================================================================
extern "C" void kernel_launch(void* const* d_in, const int* in_sizes, int n_in,
                              void* d_out, int out_size, void* d_ws, size_t ws_size,
                              hipStream_t stream)
{
    const float* R       = (const float*)d_in[0];
    const float* M       = (const float*)d_in[1];
    const float* QaAlpha = (const float*)d_in[2];
    const float* QaBeta  = (const float*)d_in[3];
    const float* em_W0   = (const float*)d_in[4];
    const float* em_b0   = (const float*)d_in[5];
    const float* em_W1   = (const float*)d_in[6];
    const float* em_b1   = (const float*)d_in[7];
    const float* em_W2   = (const float*)d_in[8];
    const float* em_b2   = (const float*)d_in[9];
    const float* iWrbf   = (const float*)d_in[10];
    const float* iWi     = (const float*)d_in[11];
    const float* ibi     = (const float*)d_in[12];
    const float* iWj     = (const float*)d_in[13];
    const float* ibj     = (const float*)d_in[14];
    const float* irW1    = (const float*)d_in[15];
    const float* irb1    = (const float*)d_in[16];
    const float* irW2    = (const float*)d_in[17];
    const float* irb2    = (const float*)d_in[18];
    const float* iWout   = (const float*)d_in[19];
    const float* ibout   = (const float*)d_in[20];
    const float* iu      = (const float*)d_in[21];
    const float* arW1    = (const float*)d_in[22];
    const float* arb1    = (const float*)d_in[23];
    const float* arW2    = (const float*)d_in[24];
    const float* arb2    = (const float*)d_in[25];
    const float* orW1    = (const float*)d_in[26];
    const float* orb1    = (const float*)d_in[27];
    const float* orW2    = (const float*)d_in[28];
    const float* orb2    = (const float*)d_in[29];
    const float* oW      = (const float*)d_in[30];
    const int*   Z       = (const int*)d_in[31];
    const int*   idx_i   = (const int*)d_in[32];
    const int*   idx_j   = (const int*)d_in[33];
    const int*   mol     = (const int*)d_in[34];

    float* out    = (float*)d_out;
    float* dij    = out + (size_t)NA*NOUT_FINAL;
    float* nh_out = dij + NE;

    float* w = (float*)d_ws;
    float* rbf  = w;  w += (size_t)NE*KR;       // 20.48M
    float* x    = w;  w += (size_t)NA*FD;
    float* xi   = w;  w += (size_t)NA*FD;
    float* xj   = w;  w += (size_t)NA*FD;
    float* mb   = w;  w += (size_t)NA*FD;
    float* tb   = w;  w += (size_t)NA*FD;
    float* xo0  = w;  w += (size_t)NA*FD;
    float* xo1  = w;  w += (size_t)NA*FD;
    float* xo2  = w;  w += (size_t)NA*FD;
    float* out4 = w;  w += (size_t)NA*4;        // ---- zero region start ----
    float* sums = w;  w += 256;                 // sQa,sFa,sQb,sFb (64 each)
    float* QAmol= w;  w += 64;
    float* QBmol= w;  w += 64;
    float* nhac = w;  w += 1;                   // ---- zero region end ----
    float* QaA  = w;  w += NA;
    float* QaB  = w;  w += NA;

    // zero: out4 + sums + QAmol + QBmol + nh  (contiguous)
    hipMemsetAsync(out4, 0, (size_t)(NA*4 + 256 + 64 + 64 + 1)*sizeof(float), stream);

    k_dij<<<(NE+255)/256, 256, 0, stream>>>(R, idx_i, idx_j, dij);
    {
        double expn = exp(-10.0);
        float gamma = (float)pow(64.0/(2.0*(1.0-expn)), 2.0);
        float mu0 = (float)expn;
        float dmu = (float)((1.0-expn)/63.0);
        k_rbf<<<(NE*KR)/256, 256, 0, stream>>>(dij, rbf, gamma, mu0, dmu);
    }
    k_init<<<(NA+255)/256, 256, 0, stream>>>(QaAlpha, QaBeta, mol, QaA, QaB, QAmol, QBmol);

    for (int j = 0; j <= 1; ++j){
        // embedding: h1 -> tb ; h2 -> xi ; x -> x
        k_embed<<<(NA*FD)/256, 256, 0, stream>>>(Z, M, QaA, QaB, em_W0, em_b0, tb);
        k_mm128<0,1,0><<<625,256,0,stream>>>(tb, em_W1, em_b1, xi, nullptr, nullptr);
        k_mm128<0,0,0><<<625,256,0,stream>>>(xi, em_W2, em_b2, x,  nullptr, nullptr);

        for (int i = 0; i < 3; ++i){
            k_mm128<1,1,0><<<625,256,0,stream>>>(x, iWi + (size_t)i*16384, ibi + i*128, xi, nullptr, nullptr);
            k_mm128<1,1,0><<<625,256,0,stream>>>(x, iWj + (size_t)i*16384, ibj + i*128, xj, nullptr, nullptr);
            k_agg<<<NA/2, 256, 0, stream>>>(rbf, iWrbf + (size_t)i*KR*FD, idx_j, xi, xj, mb);
            for (int r = 0; r < 2; ++r){   // res_int
                k_mm128<1,0,0><<<625,256,0,stream>>>(mb, irW1 + (size_t)(i*2+r)*16384, irb1 + (i*2+r)*128, tb, nullptr, nullptr);
                k_mm128<1,0,1><<<625,256,0,stream>>>(tb, irW2 + (size_t)(i*2+r)*16384, irb2 + (i*2+r)*128, mb, mb, nullptr);
            }
            k_mm128<1,0,2><<<625,256,0,stream>>>(mb, iWout + (size_t)i*16384, ibout + i*128, x, x, iu + i*128);
            for (int r = 0; r < 2; ++r){   // res_at
                k_mm128<1,0,0><<<625,256,0,stream>>>(x, arW1 + (size_t)(i*2+r)*16384, arb1 + (i*2+r)*128, tb, nullptr, nullptr);
                k_mm128<1,0,1><<<625,256,0,stream>>>(tb, arW2 + (size_t)(i*2+r)*16384, arb2 + (i*2+r)*128, x, x, nullptr);
            }
            // res_out -> xo
            float* xo = (j == 1) ? (i == 0 ? xo0 : (i == 1 ? xo1 : xo2)) : xo0;
            k_mm128<1,0,0><<<625,256,0,stream>>>(x, orW1 + (size_t)i*16384, orb1 + i*128, tb, nullptr, nullptr);
            k_mm128<1,0,1><<<625,256,0,stream>>>(tb, orW2 + (size_t)i*16384, orb2 + i*128, xo, x, nullptr);
            if (j == 0)
                k_out4<<<(NA*64)/256, 256, 0, stream>>>(xo0, oW + (size_t)i*FD*NOUTS_C, out4);
        }
        if (j == 0){
            k_molsum<<<(NA+255)/256, 256, 0, stream>>>(out4, mol, sums);
            k_qaupd<<<(NA+255)/256, 256, 0, stream>>>(out4, mol, sums, QAmol, QBmol, QaA, QaB);
        }
    }
    dim3 fg(NA/16, 8);
    k_final<<<fg, 256, 0, stream>>>(xo0, xo1, xo2, oW, out, nhac);
    k_finalize<<<1, 1, 0, stream>>>(nhac, nh_out);
}

// Round 2
// 1638.796 us; speedup vs baseline: 1.5036x; 1.5036x over previous
//
#include <hip/hip_runtime.h>
#include <math.h>

#define NA 10000
#define FD 128
#define KR 64
#define DEGC 32
#define NE (NA*DEGC)
#define NOUTS_C 2005
#define NOUT_FINAL 2001

typedef __attribute__((ext_vector_type(8))) short bh8;
typedef __attribute__((ext_vector_type(4))) float fx4;

__device__ __forceinline__ float sspf(float x){
    return fmaxf(x, 0.0f) + log1pf(expf(-fabsf(x))) - 0.6931471805599453f;
}
__device__ __forceinline__ unsigned short f2bf(float x){
    unsigned int u = __float_as_uint(x);
    unsigned int r = (u + 0x7fffu + ((u >> 16) & 1u)) >> 16;
    return (unsigned short)r;
}
__device__ __forceinline__ fx4 mfma16(bh8 a, bh8 b, fx4 c){
    return __builtin_amdgcn_mfma_f32_16x16x32_bf16(a, b, c, 0, 0, 0);
}
__device__ __forceinline__ void gll16(const void* g, void* l){
    __builtin_amdgcn_global_load_lds(
        (const __attribute__((address_space(1))) unsigned int*)g,
        (__attribute__((address_space(3))) unsigned int*)l, 16, 0, 0);
}

// ---------------- edge geometry ----------------
__global__ void k_dij(const float* __restrict__ R, const int* __restrict__ idx_i,
                      const int* __restrict__ idx_j, float* __restrict__ dij_out){
    int e = blockIdx.x*256 + threadIdx.x;
    if (e >= NE) return;
    int i = idx_i[e], j = idx_j[e];
    float dx = R[i*3+0] - R[j*3+0];
    float dy = R[i*3+1] - R[j*3+1];
    float dz = R[i*3+2] - R[j*3+2];
    dij_out[e] = sqrtf(fmaxf(dx*dx + dy*dy + dz*dz, 0.0f));
}

// rbf, written directly as bf16 swizzled LDS-image rows [e][64k]
__global__ void k_rbf_bf(const float* __restrict__ dij_in, short* __restrict__ rbf_bf,
                         float gamma, float mu0, float dmu){
    int gid = blockIdx.x*256 + threadIdx.x;   // NE*32
    int e = gid >> 5, kp = (gid & 31)*2;
    float d = dij_in[e];
    float t = d * 0.1f;
    float cut = 0.0f;
    if (d < 10.0f){
        float t2 = t*t, t3 = t2*t, t4 = t2*t2, t5 = t4*t;
        cut = 1.0f - 6.0f*t5 + 15.0f*t4 - 10.0f*t3;
    }
    float ed = expf(-d);
    float u0 = ed - (mu0 + (float)kp*dmu);
    float u1 = ed - (mu0 + (float)(kp+1)*dmu);
    float v0 = cut * expf(-gamma*u0*u0);
    float v1 = cut * expf(-gamma*u1*u1);
    unsigned int pk = (unsigned int)f2bf(v0) | ((unsigned int)f2bf(v1) << 16);
    int idx = e*64 + (((kp>>3) ^ (e&7))*8) + (kp&7);
    *(unsigned int*)&rbf_bf[idx] = pk;
}

// ---------------- init ----------------
__global__ void k_init(const float* __restrict__ QaAin, const float* __restrict__ QaBin,
                       const int* __restrict__ mol, float* __restrict__ QaA,
                       float* __restrict__ QaB, float* __restrict__ QAmol,
                       float* __restrict__ QBmol){
    int a = blockIdx.x*256 + threadIdx.x;
    if (a >= NA) return;
    float qa = QaAin[a], qb = QaBin[a];
    QaA[a] = qa; QaB[a] = qb;
    int m = mol[a];
    atomicAdd(&QAmol[m], qa);
    atomicAdd(&QBmol[m], qb);
}

// ---------------- weight conversion to bf16 swizzled images ----------------
// 128x128 mats: image[n*128 + ((k>>3)^(n&7))*8 + (k&7)]
__global__ void k_cvtW(const float* __restrict__ em_W1, const float* __restrict__ em_W2,
                       const float* __restrict__ iWi, const float* __restrict__ iWj,
                       const float* __restrict__ iWout, const float* __restrict__ irW1,
                       const float* __restrict__ irW2, const float* __restrict__ arW1,
                       const float* __restrict__ arW2, const float* __restrict__ orW1,
                       const float* __restrict__ orW2, short* __restrict__ img){
    int gid = blockIdx.x*256 + threadIdx.x;   // 41*2048
    if (gid >= 41*2048) return;
    int m = gid >> 11;
    int loc = gid & 2047;
    int n = loc >> 4, s = loc & 15;
    const float* src; int mm;
    if      (m < 1){ src = em_W1; mm = m; }
    else if (m < 2){ src = em_W2; mm = m-1; }
    else if (m < 5){ src = iWi;   mm = m-2; }
    else if (m < 8){ src = iWj;   mm = m-5; }
    else if (m < 11){ src = iWout; mm = m-8; }
    else if (m < 17){ src = irW1;  mm = m-11; }
    else if (m < 23){ src = irW2;  mm = m-17; }
    else if (m < 29){ src = arW1;  mm = m-23; }
    else if (m < 35){ src = arW2;  mm = m-29; }
    else if (m < 38){ src = orW1;  mm = m-35; }
    else            { src = orW2;  mm = m-38; }
    src += (size_t)mm * 16384;
    int kbase = (s ^ (n&7)) * 8;
    bh8 pk;
    #pragma unroll
    for (int j = 0; j < 8; ++j) pk[j] = (short)f2bf(src[(kbase+j)*128 + n]);
    *(bh8*)&img[m*16384 + n*128 + s*8] = pk;
}

// iWrbf [3][64][128] -> image[i][n*64 + ((k>>3)^(n&7))*8 + (k&7)]
__global__ void k_cvt_wrbf(const float* __restrict__ iWrbf, short* __restrict__ img){
    int gid = blockIdx.x*256 + threadIdx.x;   // 3*1024
    if (gid >= 3*1024) return;
    int i = gid >> 10;
    int loc = gid & 1023;
    int n = loc >> 3, s = loc & 7;
    const float* src = iWrbf + (size_t)i*8192;
    int kbase = (s ^ (n&7)) * 8;
    bh8 pk;
    #pragma unroll
    for (int j = 0; j < 8; ++j) pk[j] = (short)f2bf(src[(kbase+j)*128 + n]);
    *(bh8*)&img[i*8192 + n*64 + s*8] = pk;
}

// oW [3][128][2005] -> image[kk][n][32k]: [kk*2048*32 + n*32 + ((kl>>3)^(n&3))*8 + (kl&7)]
__global__ void k_cvt_oW(const float* __restrict__ oW, short* __restrict__ img){
    int gid = blockIdx.x*256 + threadIdx.x;   // 12*2048*4
    if (gid >= 12*2048*4) return;
    int kk = gid >> 13;
    int loc = gid & 8191;
    int n = loc >> 2, s = loc & 3;
    int seg = kk >> 2;
    int kbase = (s ^ (n&3)) * 8;
    bh8 pk;
    #pragma unroll
    for (int j = 0; j < 8; ++j){
        int kseg = (kk&3)*32 + kbase + j;     // 0..127
        float v = (n < NOUTS_C) ? oW[((size_t)seg*128 + kseg)*NOUTS_C + n] : 0.0f;
        pk[j] = (short)f2bf(v);
    }
    *(bh8*)&img[((size_t)kk*2048 + n)*32 + s*8] = pk;
}

// ---------------- embedding first layer (K=4) ----------------
__global__ void k_embed(const int* __restrict__ Z, const float* __restrict__ M,
                        const float* __restrict__ QaA, const float* __restrict__ QaB,
                        const float* __restrict__ W0, const float* __restrict__ b0,
                        float* __restrict__ h1){
    int gid = blockIdx.x*256 + threadIdx.x;
    if (gid >= NA*FD) return;
    int a = gid >> 7, c = gid & 127;
    float f0 = (float)Z[a], f1 = M[a], f2 = QaA[a], f3 = QaB[a];
    float v = b0[c] + f0*W0[c] + f1*W0[128+c] + f2*W0[256+c] + f3*W0[384+c];
    h1[gid] = sspf(v);
}

// ---------------- MFMA GEMM, BM=16, optional fused second GEMM ----------------
// MODE 0: chain (em):      Y1 = ssp(A@W1+b1) @ W2 + b2
// MODE 1: chain+add (res): Y1 = add + ssp(A@W1+b1) @ W2 + b2
// MODE 2: dual (xi/xj):    Y1 = ssp(A@W1+b1); Y2 = ssp(A@W2+b2)
// MODE 3: single+scale:    Y1 = scale*add + A@W1 + b1
// A = ssp(X) if A_SSP else X
template<int A_SSP, int MODE>
__global__ __launch_bounds__(256) void k_gemm16(
    const float* __restrict__ X, const short* __restrict__ W1i, const float* __restrict__ b1,
    const short* __restrict__ W2i, const float* __restrict__ b2,
    float* __restrict__ Y1, float* __restrict__ Y2,
    const float* __restrict__ add_src, const float* __restrict__ scale_vec)
{
    __shared__ short W1s[16384];
    __shared__ short W2s[16384];
    __shared__ short As[2048];
    __shared__ short Ts[2048];
    const int tid = threadIdx.x;
    const int wv = tid >> 6, ln = tid & 63;
    const int a0 = blockIdx.x * 16;            // 625 blocks exact
    // stage weights via global_load_lds (linear; images pre-swizzled)
    {
        const char* g1 = (const char*)W1i; char* l1 = (char*)W1s;
        #pragma unroll
        for (int i = 0; i < 8; ++i){
            int off = wv*8192 + i*1024;
            gll16(g1 + off + ln*16, l1 + off);
        }
        if (MODE != 3){
            const char* g2 = (const char*)W2i; char* l2 = (char*)W2s;
            #pragma unroll
            for (int i = 0; i < 8; ++i){
                int off = wv*8192 + i*1024;
                gll16(g2 + off + ln*16, l2 + off);
            }
        }
    }
    // stage A (ssp + bf16, swizzled)
    {
        int m = tid >> 4, s = tid & 15;
        const float* xr = X + (size_t)(a0+m)*FD + s*8;
        float4 u = *(const float4*)xr;
        float4 v = *(const float4*)(xr + 4);
        if (A_SSP){
            u.x=sspf(u.x); u.y=sspf(u.y); u.z=sspf(u.z); u.w=sspf(u.w);
            v.x=sspf(v.x); v.y=sspf(v.y); v.z=sspf(v.z); v.w=sspf(v.w);
        }
        bh8 pk;
        pk[0]=(short)f2bf(u.x); pk[1]=(short)f2bf(u.y); pk[2]=(short)f2bf(u.z); pk[3]=(short)f2bf(u.w);
        pk[4]=(short)f2bf(v.x); pk[5]=(short)f2bf(v.y); pk[6]=(short)f2bf(v.z); pk[7]=(short)f2bf(v.w);
        *(bh8*)&As[m*128 + ((s ^ (m&7))*8)] = pk;
    }
    __syncthreads();
    const int g = ln >> 4, l15 = ln & 15;
    bh8 a[4];
    #pragma unroll
    for (int kk = 0; kk < 4; ++kk)
        a[kk] = *(const bh8*)&As[l15*128 + (((kk*4+g) ^ (l15&7))*8)];
    fx4 acc0 = {0,0,0,0}, acc1 = {0,0,0,0};
    #pragma unroll
    for (int kk = 0; kk < 4; ++kk){
        int n0 = wv*32 + l15;
        bh8 b0v = *(const bh8*)&W1s[n0*128 + (((kk*4+g) ^ (n0&7))*8)];
        acc0 = mfma16(a[kk], b0v, acc0);
        int n1 = n0 + 16;
        bh8 b1v = *(const bh8*)&W1s[n1*128 + (((kk*4+g) ^ (n1&7))*8)];
        acc1 = mfma16(a[kk], b1v, acc1);
    }
    const int col0 = wv*32 + l15, col1 = col0 + 16;

    if (MODE == 0 || MODE == 1){
        float bb0 = b1[col0], bb1 = b1[col1];
        #pragma unroll
        for (int r = 0; r < 4; ++r){
            int row = g*4 + r;
            float t0 = sspf(acc0[r] + bb0);
            float t1 = sspf(acc1[r] + bb1);
            Ts[row*128 + (((col0>>3) ^ (row&7))*8) + (col0&7)] = (short)f2bf(t0);
            Ts[row*128 + (((col1>>3) ^ (row&7))*8) + (col1&7)] = (short)f2bf(t1);
        }
        __syncthreads();
        bh8 a2[4];
        #pragma unroll
        for (int kk = 0; kk < 4; ++kk)
            a2[kk] = *(const bh8*)&Ts[l15*128 + (((kk*4+g) ^ (l15&7))*8)];
        fx4 c0 = {0,0,0,0}, c1 = {0,0,0,0};
        #pragma unroll
        for (int kk = 0; kk < 4; ++kk){
            bh8 b0v = *(const bh8*)&W2s[col0*128 + (((kk*4+g) ^ (col0&7))*8)];
            c0 = mfma16(a2[kk], b0v, c0);
            bh8 b1v = *(const bh8*)&W2s[col1*128 + (((kk*4+g) ^ (col1&7))*8)];
            c1 = mfma16(a2[kk], b1v, c1);
        }
        float bc0 = b2[col0], bc1 = b2[col1];
        #pragma unroll
        for (int r = 0; r < 4; ++r){
            int ga = a0 + g*4 + r;
            float v0 = c0[r] + bc0;
            float v1 = c1[r] + bc1;
            if (MODE == 1){
                v0 += add_src[(size_t)ga*FD + col0];
                v1 += add_src[(size_t)ga*FD + col1];
            }
            Y1[(size_t)ga*FD + col0] = v0;
            Y1[(size_t)ga*FD + col1] = v1;
        }
    } else if (MODE == 2){
        float bb0 = b1[col0], bb1 = b1[col1];
        #pragma unroll
        for (int r = 0; r < 4; ++r){
            int ga = a0 + g*4 + r;
            Y1[(size_t)ga*FD + col0] = sspf(acc0[r] + bb0);
            Y1[(size_t)ga*FD + col1] = sspf(acc1[r] + bb1);
        }
        fx4 c0 = {0,0,0,0}, c1 = {0,0,0,0};
        #pragma unroll
        for (int kk = 0; kk < 4; ++kk){
            bh8 b0v = *(const bh8*)&W2s[col0*128 + (((kk*4+g) ^ (col0&7))*8)];
            c0 = mfma16(a[kk], b0v, c0);
            bh8 b1v = *(const bh8*)&W2s[col1*128 + (((kk*4+g) ^ (col1&7))*8)];
            c1 = mfma16(a[kk], b1v, c1);
        }
        float bc0 = b2[col0], bc1 = b2[col1];
        #pragma unroll
        for (int r = 0; r < 4; ++r){
            int ga = a0 + g*4 + r;
            Y2[(size_t)ga*FD + col0] = sspf(c0[r] + bc0);
            Y2[(size_t)ga*FD + col1] = sspf(c1[r] + bc1);
        }
    } else { // MODE 3
        float bb0 = b1[col0], bb1 = b1[col1];
        float s0 = scale_vec[col0], s1 = scale_vec[col1];
        #pragma unroll
        for (int r = 0; r < 4; ++r){
            int ga = a0 + g*4 + r;
            Y1[(size_t)ga*FD + col0] = acc0[r] + bb0 + s0*add_src[(size_t)ga*FD + col0];
            Y1[(size_t)ga*FD + col1] = acc1[r] + bb1 + s1*add_src[(size_t)ga*FD + col1];
        }
    }
}

// ---------------- message aggregation (MFMA): m = xi + seg_sum(g * xj[idx_j]) ----------------
__global__ __launch_bounds__(256) void k_agg_mfma(
    const short* __restrict__ rbf_bf, const short* __restrict__ wri,
    const int* __restrict__ idxj, const float* __restrict__ xi,
    const float* __restrict__ xj, float* __restrict__ mout)
{
    __shared__ short Rb[256*64];   // 32 KB
    __shared__ short Wr[128*64];   // 16 KB
    __shared__ int Jd[256];
    const int tid = threadIdx.x;
    const int wv = tid >> 6, ln = tid & 63;
    const int e0 = blockIdx.x * 256;           // 1250 blocks exact
    {
        const char* g = (const char*)(rbf_bf + (size_t)e0*64);
        char* l = (char*)Rb;
        #pragma unroll
        for (int i = 0; i < 8; ++i){
            int off = wv*8192 + i*1024;
            gll16(g + off + ln*16, l + off);
        }
        const char* g2 = (const char*)wri;
        char* l2 = (char*)Wr;
        #pragma unroll
        for (int i = 0; i < 4; ++i){
            int off = wv*4096 + i*1024;
            gll16(g2 + off + ln*16, l2 + off);
        }
        Jd[tid] = idxj[e0 + tid];
    }
    __syncthreads();
    const int g = ln >> 4, l15 = ln & 15;
    bh8 a[4][2];
    #pragma unroll
    for (int mt = 0; mt < 4; ++mt){
        int el = wv*64 + mt*16 + l15;
        #pragma unroll
        for (int kk = 0; kk < 2; ++kk)
            a[mt][kk] = *(const bh8*)&Rb[el*64 + (((kk*4+g) ^ (el&7))*8)];
    }
    float pa[2][8];
    #pragma unroll
    for (int q = 0; q < 8; ++q){ pa[0][q]=0.f; pa[1][q]=0.f; }
    #pragma unroll
    for (int h = 0; h < 2; ++h){
        fx4 acc[4][4];
        #pragma unroll
        for (int mt = 0; mt < 4; ++mt)
            #pragma unroll
            for (int nt = 0; nt < 4; ++nt) acc[mt][nt] = (fx4){0,0,0,0};
        #pragma unroll
        for (int kk = 0; kk < 2; ++kk){
            #pragma unroll
            for (int nt = 0; nt < 4; ++nt){
                int n = h*64 + nt*16 + l15;
                bh8 b = *(const bh8*)&Wr[n*64 + (((kk*4+g) ^ (n&7))*8)];
                #pragma unroll
                for (int mt = 0; mt < 4; ++mt)
                    acc[mt][nt] = mfma16(a[mt][kk], b, acc[mt][nt]);
            }
        }
        #pragma unroll
        for (int mt = 0; mt < 4; ++mt){
            int at = mt >> 1;
            int jv[4];
            #pragma unroll
            for (int r = 0; r < 4; ++r) jv[r] = Jd[wv*64 + mt*16 + g*4 + r];
            #pragma unroll
            for (int nt = 0; nt < 4; ++nt){
                int col = h*64 + nt*16 + l15;
                float s = 0.f;
                #pragma unroll
                for (int r = 0; r < 4; ++r)
                    s += acc[mt][nt][r] * xj[(size_t)jv[r]*FD + col];
                pa[at][h*4+nt] += s;
            }
        }
    }
    #pragma unroll
    for (int at = 0; at < 2; ++at)
        #pragma unroll
        for (int q = 0; q < 8; ++q){
            float v = pa[at][q];
            v += __shfl_xor(v, 16);
            v += __shfl_xor(v, 32);
            pa[at][q] = v;
        }
    if (g == 0){
        #pragma unroll
        for (int at = 0; at < 2; ++at){
            int ga = blockIdx.x*8 + wv*2 + at;
            #pragma unroll
            for (int q = 0; q < 8; ++q){
                int col = (q>>2)*64 + (q&3)*16 + l15;
                mout[(size_t)ga*FD + col] = xi[(size_t)ga*FD + col] + pa[at][q];
            }
        }
    }
}

// ---------------- j=0: out4 += ssp(xo) @ oW_i[:, 0:4] (f32, cheap) ----------------
__global__ void k_out4(const float* __restrict__ xo, const float* __restrict__ oWi,
                       float* __restrict__ out4){
    int gid = blockIdx.x*256 + threadIdx.x;
    int a = gid >> 6;
    int lane = threadIdx.x & 63;
    if (a >= NA) return;
    float y0 = sspf(xo[(size_t)a*FD + lane]);
    float y1 = sspf(xo[(size_t)a*FD + lane + 64]);
    const float* w0 = oWi + (size_t)lane*NOUTS_C;
    const float* w1 = oWi + (size_t)(lane+64)*NOUTS_C;
    float p0 = y0*w0[0] + y1*w1[0];
    float p1 = y0*w0[1] + y1*w1[1];
    float p2 = y0*w0[2] + y1*w1[2];
    float p3 = y0*w0[3] + y1*w1[3];
    #pragma unroll
    for (int off = 32; off > 0; off >>= 1){
        p0 += __shfl_down(p0, off);
        p1 += __shfl_down(p1, off);
        p2 += __shfl_down(p2, off);
        p3 += __shfl_down(p3, off);
    }
    if (lane == 0){
        out4[a*4+0] += p0; out4[a*4+1] += p1;
        out4[a*4+2] += p2; out4[a*4+3] += p3;
    }
}

// ---------------- charge equilibration ----------------
__global__ void k_molsum(const float* __restrict__ out4, const int* __restrict__ mol,
                         float* __restrict__ sums){
    int a = blockIdx.x*256 + threadIdx.x;
    if (a >= NA) return;
    int m = mol[a];
    atomicAdd(&sums[m],     out4[a*4+0]);
    atomicAdd(&sums[64+m],  out4[a*4+1]);
    atomicAdd(&sums[128+m], out4[a*4+2]);
    atomicAdd(&sums[192+m], out4[a*4+3]);
}

__global__ void k_qaupd(const float* __restrict__ out4, const int* __restrict__ mol,
                        const float* __restrict__ sums, const float* __restrict__ QAmol,
                        const float* __restrict__ QBmol, float* __restrict__ QaA,
                        float* __restrict__ QaB){
    int a = blockIdx.x*256 + threadIdx.x;
    if (a >= NA) return;
    int m = mol[a];
    float qa_n = out4[a*4+0], fa = out4[a*4+1];
    float qb_n = out4[a*4+2], fb = out4[a*4+3];
    QaA[a] = qa_n + fa * ((QAmol[m] - sums[m])     / sums[64+m]);
    QaB[a] = qb_n + fb * ((QBmol[m] - sums[128+m]) / sums[192+m]);
}

// ---------------- final fused head (j=1): MFMA, outputs + nhloss ----------------
// grid (157, 16): BM=64 rows, 128 cols per block, K=384 in 12 chunks of 32
__global__ __launch_bounds__(256) void k_final_mfma(
    const float* __restrict__ xo0, const float* __restrict__ xo1,
    const float* __restrict__ xo2, const short* __restrict__ oW_img,
    float* __restrict__ outp, float* __restrict__ nh_acc)
{
    __shared__ short As[64*384];   // 48 KB
    __shared__ short Bs[128*32];   // 8 KB
    const int tid = threadIdx.x;
    const int wv = tid >> 6, ln = tid & 63;
    const int a0 = blockIdx.x * 64;
    const int cg = blockIdx.y;
    // stage A: ssp(xo) bf16 swizzled, rows beyond NA zero
    for (int it = 0; it < 12; ++it){
        int f = it*256 + tid;       // 64*48
        int row = f / 48, s = f - row*48;
        int seg = s >> 4, kloc = (s & 15)*8;
        const float* src = (seg == 0) ? xo0 : ((seg == 1) ? xo1 : xo2);
        int ga = a0 + row;
        bh8 pk;
        if (ga < NA){
            const float* xr = src + (size_t)ga*FD + kloc;
            float4 u = *(const float4*)xr;
            float4 v = *(const float4*)(xr + 4);
            pk[0]=(short)f2bf(sspf(u.x)); pk[1]=(short)f2bf(sspf(u.y));
            pk[2]=(short)f2bf(sspf(u.z)); pk[3]=(short)f2bf(sspf(u.w));
            pk[4]=(short)f2bf(sspf(v.x)); pk[5]=(short)f2bf(sspf(v.y));
            pk[6]=(short)f2bf(sspf(v.z)); pk[7]=(short)f2bf(sspf(v.w));
        } else {
            #pragma unroll
            for (int j = 0; j < 8; ++j) pk[j] = 0;
        }
        *(bh8*)&As[row*384 + ((s ^ (row&7))*8)] = pk;
    }
    const int g = ln >> 4, l15 = ln & 15;
    const int arow = 16*wv + l15;
    fx4 osum[8], p2[8];
    #pragma unroll
    for (int nt = 0; nt < 8; ++nt){ osum[nt] = (fx4){0,0,0,0}; p2[nt] = (fx4){0,0,0,0}; }
    float nh = 0.f;
    for (int seg = 0; seg < 3; ++seg){
        fx4 acc[8];
        #pragma unroll
        for (int nt = 0; nt < 8; ++nt) acc[nt] = (fx4){0,0,0,0};
        for (int kkl = 0; kkl < 4; ++kkl){
            int kk = seg*4 + kkl;
            // stage B chunk
            {
                const char* gsrc = (const char*)(oW_img + ((size_t)kk*2048 + cg*128)*32);
                char* l = (char*)Bs;
                #pragma unroll
                for (int i = 0; i < 2; ++i){
                    int off = wv*2048 + i*1024;
                    gll16(gsrc + off + ln*16, l + off);
                }
            }
            __syncthreads();
            bh8 af = *(const bh8*)&As[arow*384 + (((kk*4+g) ^ (arow&7))*8)];
            #pragma unroll
            for (int nt = 0; nt < 8; ++nt){
                int n = nt*16 + l15;
                bh8 bf = *(const bh8*)&Bs[n*32 + ((g ^ (n&3))*8)];
                acc[nt] = mfma16(af, bf, acc[nt]);
            }
            __syncthreads();
        }
        // per-seg epilogue
        #pragma unroll
        for (int nt = 0; nt < 8; ++nt){
            #pragma unroll
            for (int r = 0; r < 4; ++r){
                float o = acc[nt][r];
                osum[nt][r] += o;
                if (seg > 0){
                    int A = a0 + 16*wv + g*4 + r;
                    int col = cg*128 + nt*16 + l15;
                    if (A >= 4 && A < NA && col < NOUTS_C){
                        float o2 = o*o;
                        float p = p2[nt][r];
                        nh += o2 / (o2 + p + 1e-7f);
                    }
                }
                p2[nt][r] = o*o;
            }
        }
    }
    // stores
    #pragma unroll
    for (int nt = 0; nt < 8; ++nt){
        #pragma unroll
        for (int r = 0; r < 4; ++r){
            int A = a0 + 16*wv + g*4 + r;
            int col = cg*128 + nt*16 + l15;
            if (A < NA && col >= 4 && col < NOUTS_C){
                float v = osum[nt][r];
                if (col > 4) v = fmaxf(v, 0.f);
                outp[(size_t)A*NOUT_FINAL + (col - 4)] = v;
            }
        }
    }
    #pragma unroll
    for (int off = 32; off > 0; off >>= 1) nh += __shfl_down(nh, off);
    if (ln == 0) atomicAdd(nh_acc, nh);
}

__global__ void k_finalize(const float* __restrict__ nh_acc, float* __restrict__ nh_out){
    *nh_out = *nh_acc * (1.0f / (float)((NA - 4) * NOUTS_C));
}

// =====================================================================
extern "C" void kernel_launch(void* const* d_in, const int* in_sizes, int n_in,
                              void* d_out, int out_size, void* d_ws, size_t ws_size,
                              hipStream_t stream)
{
    const float* R       = (const float*)d_in[0];
    const float* M       = (const float*)d_in[1];
    const float* QaAlpha = (const float*)d_in[2];
    const float* QaBeta  = (const float*)d_in[3];
    const float* em_W0   = (const float*)d_in[4];
    const float* em_b0   = (const float*)d_in[5];
    const float* em_W1   = (const float*)d_in[6];
    const float* em_b1   = (const float*)d_in[7];
    const float* em_W2   = (const float*)d_in[8];
    const float* em_b2   = (const float*)d_in[9];
    const float* iWrbf   = (const float*)d_in[10];
    const float* iWi     = (const float*)d_in[11];
    const float* ibi     = (const float*)d_in[12];
    const float* iWj     = (const float*)d_in[13];
    const float* ibj     = (const float*)d_in[14];
    const float* irW1    = (const float*)d_in[15];
    const float* irb1    = (const float*)d_in[16];
    const float* irW2    = (const float*)d_in[17];
    const float* irb2    = (const float*)d_in[18];
    const float* iWout   = (const float*)d_in[19];
    const float* ibout   = (const float*)d_in[20];
    const float* iu      = (const float*)d_in[21];
    const float* arW1    = (const float*)d_in[22];
    const float* arb1    = (const float*)d_in[23];
    const float* arW2    = (const float*)d_in[24];
    const float* arb2    = (const float*)d_in[25];
    const float* orW1    = (const float*)d_in[26];
    const float* orb1    = (const float*)d_in[27];
    const float* orW2    = (const float*)d_in[28];
    const float* orb2    = (const float*)d_in[29];
    const float* oW      = (const float*)d_in[30];
    const int*   Z       = (const int*)d_in[31];
    const int*   idx_i   = (const int*)d_in[32];
    const int*   idx_j   = (const int*)d_in[33];
    const int*   mol     = (const int*)d_in[34];

    float* out    = (float*)d_out;
    float* dij    = out + (size_t)NA*NOUT_FINAL;
    float* nh_out = dij + NE;

    // ---- workspace layout: f32 region, then 64B-aligned bf16 region ----
    float* fbase = (float*)d_ws;
    size_t fo = 0;
    float* x    = fbase + fo; fo += (size_t)NA*FD;
    float* xi   = fbase + fo; fo += (size_t)NA*FD;
    float* xj   = fbase + fo; fo += (size_t)NA*FD;
    float* mb   = fbase + fo; fo += (size_t)NA*FD;
    float* tb   = fbase + fo; fo += (size_t)NA*FD;
    float* xo0  = fbase + fo; fo += (size_t)NA*FD;
    float* xo1  = fbase + fo; fo += (size_t)NA*FD;
    float* xo2  = fbase + fo; fo += (size_t)NA*FD;
    float* out4 = fbase + fo; fo += (size_t)NA*4;   // zero region start
    float* sums = fbase + fo; fo += 256;
    float* QAmol= fbase + fo; fo += 64;
    float* QBmol= fbase + fo; fo += 64;
    float* nhac = fbase + fo; fo += 1;              // zero region end
    float* QaA  = fbase + fo; fo += NA;
    float* QaB  = fbase + fo; fo += NA;
    size_t sboff = ((fo*4 + 63) / 64) * 64;
    short* sbase = (short*)((char*)d_ws + sboff);
    size_t so = 0;
    short* rbf_bf = sbase + so; so += (size_t)NE*64;
    short* wmat   = sbase + so; so += (size_t)41*16384;
    short* wrbf   = sbase + so; so += (size_t)3*8192;
    short* oWimg  = sbase + so; so += (size_t)12*2048*32;

    hipMemsetAsync(out4, 0, (size_t)(NA*4 + 256 + 64 + 64 + 1)*sizeof(float), stream);

    // weight conversion (runs every call; ~1.5M elems)
    k_cvtW<<<(41*2048+255)/256, 256, 0, stream>>>(em_W1, em_W2, iWi, iWj, iWout,
                                                  irW1, irW2, arW1, arW2, orW1, orW2, wmat);
    k_cvt_wrbf<<<(3*1024+255)/256, 256, 0, stream>>>(iWrbf, wrbf);
    k_cvt_oW<<<(12*2048*4)/256, 256, 0, stream>>>(oW, oWimg);

    k_dij<<<(NE+255)/256, 256, 0, stream>>>(R, idx_i, idx_j, dij);
    {
        double expn = exp(-10.0);
        float gamma = (float)pow(64.0/(2.0*(1.0-expn)), 2.0);
        float mu0 = (float)expn;
        float dmu = (float)((1.0-expn)/63.0);
        k_rbf_bf<<<(NE*32)/256, 256, 0, stream>>>(dij, rbf_bf, gamma, mu0, dmu);
    }
    k_init<<<(NA+255)/256, 256, 0, stream>>>(QaAlpha, QaBeta, mol, QaA, QaB, QAmol, QBmol);

    for (int j = 0; j <= 1; ++j){
        k_embed<<<(NA*FD)/256, 256, 0, stream>>>(Z, M, QaA, QaB, em_W0, em_b0, tb);
        // em chain: x = ssp(tb@W1+b1)@W2+b2
        k_gemm16<0,0><<<625,256,0,stream>>>(tb, wmat + 0*16384, em_b1,
                                            wmat + 1*16384, em_b2, x, nullptr, nullptr, nullptr);
        for (int i = 0; i < 3; ++i){
            // dual: xi, xj
            k_gemm16<1,2><<<625,256,0,stream>>>(x, wmat + (size_t)(2+i)*16384, ibi + i*128,
                                                wmat + (size_t)(5+i)*16384, ibj + i*128,
                                                xi, xj, nullptr, nullptr);
            k_agg_mfma<<<1250,256,0,stream>>>(rbf_bf, wrbf + (size_t)i*8192, idx_j, xi, xj, mb);
            for (int r = 0; r < 2; ++r){
                int mi = i*2 + r;
                k_gemm16<1,1><<<625,256,0,stream>>>(mb, wmat + (size_t)(11+mi)*16384, irb1 + mi*128,
                                                    wmat + (size_t)(17+mi)*16384, irb2 + mi*128,
                                                    mb, nullptr, mb, nullptr);
            }
            k_gemm16<1,3><<<625,256,0,stream>>>(mb, wmat + (size_t)(8+i)*16384, ibout + i*128,
                                                nullptr, nullptr, x, nullptr, x, iu + i*128);
            for (int r = 0; r < 2; ++r){
                int mi = i*2 + r;
                k_gemm16<1,1><<<625,256,0,stream>>>(x, wmat + (size_t)(23+mi)*16384, arb1 + mi*128,
                                                    wmat + (size_t)(29+mi)*16384, arb2 + mi*128,
                                                    x, nullptr, x, nullptr);
            }
            float* xo = (j == 1) ? (i == 0 ? xo0 : (i == 1 ? xo1 : xo2)) : xo0;
            k_gemm16<1,1><<<625,256,0,stream>>>(x, wmat + (size_t)(35+i)*16384, orb1 + i*128,
                                                wmat + (size_t)(38+i)*16384, orb2 + i*128,
                                                xo, nullptr, x, nullptr);
            if (j == 0)
                k_out4<<<(NA*64)/256, 256, 0, stream>>>(xo0, oW + (size_t)i*FD*NOUTS_C, out4);
        }
        if (j == 0){
            k_molsum<<<(NA+255)/256, 256, 0, stream>>>(out4, mol, sums);
            k_qaupd<<<(NA+255)/256, 256, 0, stream>>>(out4, mol, sums, QAmol, QBmol, QaA, QaB);
        }
    }
    dim3 fg(157, 16);
    k_final_mfma<<<fg, 256, 0, stream>>>(xo0, xo1, xo2, oWimg, out, nhac);
    k_finalize<<<1, 1, 0, stream>>>(nhac, nh_out);
}